// Round 16
// baseline (148.326 us; speedup 1.0000x reference)
//
#include <hip/hip_runtime.h>

#define B_ 8
#define S_ 1024
#define E_ 768
#define H_ 12
#define D_ 64
#define HD_ 768
#define SCALE_ 0.125f

typedef short s16x8 __attribute__((ext_vector_type(8)));
typedef float f32x4 __attribute__((ext_vector_type(4)));
typedef unsigned int u32x4 __attribute__((ext_vector_type(4)));
typedef unsigned short u16;
typedef unsigned int u32;

#define MFMA16(a,b,c) __builtin_amdgcn_mfma_f32_16x16x32_bf16((a),(b),(c),0,0,0)

__device__ __forceinline__ u16 f2bf(float x){
  unsigned u = __float_as_uint(x);
  u += 0x7fffu + ((u >> 16) & 1u);
  return (u16)(u >> 16);
}

__device__ __forceinline__ u32 pack2(float a, float b){
  return (u32)f2bf(a) | ((u32)f2bf(b) << 16);
}

// HW packed f32->bf16 (RNE). No builtin on gfx950 (m240) -> inline asm.
__device__ __forceinline__ u32 cvtpk(float a, float b){
  u32 r;
  asm("v_cvt_pk_bf16_f32 %0, %1, %2" : "=v"(r) : "v"(a), "v"(b));
  return r;
}

#define GLOAD_LDS16(srcp, dstp)                                                        \
  __builtin_amdgcn_global_load_lds(                                                    \
      (const __attribute__((address_space(1))) u32*)(srcp),                            \
      (__attribute__((address_space(3))) u32*)(dstp), 16, 0, 0)

// ---------------------------------------------------------------------------
// Weight prep (coalesced, LDS 64x65 transpose tiles):
//   blocks 0..431 : Wq/Wk/Wv [H,E,D] -> Wt_qkv[z][n=h*64+d][e]
//   blocks 432..575: Wo [HD,E] -> Wot[n][k]
// ---------------------------------------------------------------------------
__global__ void prep_weights(const float* __restrict__ Wq, const float* __restrict__ Wk,
                             const float* __restrict__ Wv, const float* __restrict__ Wo,
                             u16* __restrict__ Wt_qkv, u16* __restrict__ Wot) {
  __shared__ float t[64][65];
  const int bid = blockIdx.x;
  const int tid = threadIdx.x;
  const int c = tid & 63;
  const int rg = tid >> 6;
  if (bid < 432) {
    int z = bid / 144, r = bid % 144, h = r / 12, et = r % 12;
    const float* W = (z == 0) ? Wq : ((z == 1) ? Wk : Wv);
    const float* src = W + (size_t)(h * E_ + et * 64) * D_;
#pragma unroll
    for (int p = 0; p < 16; ++p)
      t[rg + 4 * p][c] = src[(rg + 4 * p) * D_ + c];
    __syncthreads();
    u16* dst = Wt_qkv + (size_t)z * HD_ * E_ + (h * 64) * E_ + et * 64;
#pragma unroll
    for (int p = 0; p < 16; ++p) {
      int d = rg + 4 * p;
      dst[d * E_ + c] = f2bf(t[c][d]);
    }
  } else {
    int r = bid - 432; int kt = r / 12, nt = r % 12;
    const float* src = Wo + (size_t)(kt * 64) * E_ + nt * 64;
#pragma unroll
    for (int p = 0; p < 16; ++p)
      t[rg + 4 * p][c] = src[(rg + 4 * p) * E_ + c];
    __syncthreads();
    u16* dst = Wot + (size_t)(nt * 64) * HD_ + kt * 64;
#pragma unroll
    for (int p = 0; p < 16; ++p) {
      int nl = rg + 4 * p;
      dst[nl * HD_ + c] = f2bf(t[c][nl]);
    }
  }
}

// ---------------------------------------------------------------------------
// QKV projection GEMM (round-12 body) with A-reuse grid order: grid (6,64,3),
// n-panel = blockIdx.x (fastest), m-block = blockIdx.y. The 6 consumers of
// each A-tile are now consecutive linear blocks (adjacent in dispatch, spread
// over XCDs) -> A is HBM-fetched once and L3/L2-hot for the other 5 reads,
// shortening the staging-miss latency that bounds the single-buffer loop.
// LDS-bounce epilogue unchanged. 49KB -> 3 blocks/CU.
// z==0 -> Qbf [B,H,S,D] (pre-scaled); z==1 -> Kbf; z==2 -> Vt [B,H,D,S].
// ---------------------------------------------------------------------------
__launch_bounds__(256)
__global__ void qkv_gemm(const float* __restrict__ qin, const float* __restrict__ kin,
                         const float* __restrict__ vin, const u16* __restrict__ Wt_qkv,
                         const float* __restrict__ bq, const float* __restrict__ bk,
                         const float* __restrict__ bv, u16* __restrict__ Qbf,
                         u16* __restrict__ Kbf, u16* __restrict__ Vt) {
  __shared__ __align__(16) u16 SMEM[128 * 132];   // 33 KB: fp32 A tile / C bounce
  __shared__ __align__(16) u16 Bs[128 * 64];      // 16 KB bf16 B tile
  float* Asf = (float*)SMEM;                      // first 32 KB during K-loop
  const int tid = threadIdx.x;
  const int lane = tid & 63;
  const int w = tid >> 6;
  const int wr = w >> 1, wc = w & 1;
  const int m0 = blockIdx.y * 128;                // m from y (A reused across x)
  const int n0 = blockIdx.x * 128;                // n-panel varies fastest
  const int z  = blockIdx.z;
  const float* in = (z == 0) ? qin : ((z == 1) ? kin : vin);
  const u16* Wt = Wt_qkv + z * (HD_ * E_);
  const float* bias = (z == 0) ? bq : ((z == 1) ? bk : bv);

  f32x4 acc[4][4];
#pragma unroll
  for (int i = 0; i < 4; ++i)
#pragma unroll
    for (int j = 0; j < 4; ++j) acc[i][j] = (f32x4){0.f, 0.f, 0.f, 0.f};

  const int g = lane >> 4;
  const int l15 = lane & 15;
  const int arow = lane >> 4;          // 0..3 within 4-row slab
  const int ach  = lane & 15;          // 16B chunk within 256B row
  const int brow = lane >> 3;          // 0..7
  const int bch  = lane & 7;

  for (int kt = 0; kt < E_ / 64; ++kt) {
    __syncthreads();
#pragma unroll
    for (int i = 0; i < 8; ++i) {       // A: 128 rows, 4 per wave-pass
      int row = i * 16 + w * 4 + arow;
      GLOAD_LDS16(in + (size_t)(m0 + row) * E_ + kt * 64 + ((ach ^ (row & 15)) << 2),
                  &Asf[(i * 16 + w * 4) * 64]);
    }
#pragma unroll
    for (int j = 0; j < 4; ++j) {       // B: 128 rows, 8 per wave-pass
      int row = j * 32 + w * 8 + brow;
      GLOAD_LDS16(Wt + (n0 + row) * E_ + kt * 64 + ((bch ^ (row & 7)) << 3),
                  &Bs[(j * 32 + w * 8) * 64]);
    }
    __syncthreads();
#pragma unroll
    for (int kk = 0; kk < 2; ++kk) {
      const int kc = kk * 4 + g;
      s16x8 af[4], bfr[4];
#pragma unroll
      for (int i = 0; i < 4; ++i) {
        int row = wr * 64 + i * 16 + l15;
        const float* rp = Asf + row * 64;
        f32x4 lo = *(const f32x4*)(rp + (((2 * kc)     ^ (row & 15)) << 2));
        f32x4 hi = *(const f32x4*)(rp + (((2 * kc + 1) ^ (row & 15)) << 2));
        u32x4 q;
        q[0] = cvtpk(lo[0], lo[1]);
        q[1] = cvtpk(lo[2], lo[3]);
        q[2] = cvtpk(hi[0], hi[1]);
        q[3] = cvtpk(hi[2], hi[3]);
        af[i] = __builtin_bit_cast(s16x8, q);
      }
#pragma unroll
      for (int j = 0; j < 4; ++j) {
        int row = wc * 64 + j * 16 + l15;
        bfr[j] = *(const s16x8*)(Bs + row * 64 + ((kc ^ (row & 7)) << 3));
      }
#pragma unroll
      for (int i = 0; i < 4; ++i)
#pragma unroll
        for (int j = 0; j < 4; ++j) acc[i][j] = MFMA16(af[i], bfr[j], acc[i][j]);
    }
  }
  // ---- epilogue: LDS bounce -> coalesced row stores.
  __syncthreads();                       // close all K-loop LDS reads
  const int bb = m0 >> 10;
  const int s0 = m0 & 1023;
  u16* Ct = SMEM;                        // [row][132] padded bounce tile
  if (z == 2) {
#pragma unroll
    for (int j = 0; j < 4; ++j) {
      int nl = wc * 64 + j * 16 + l15;
      float bvv = bias[n0 + nl];
#pragma unroll
      for (int i = 0; i < 4; ++i) {
        uint2 pk = make_uint2(pack2(acc[i][j][0] + bvv, acc[i][j][1] + bvv),
                              pack2(acc[i][j][2] + bvv, acc[i][j][3] + bvv));
        *(uint2*)(Ct + nl * 132 + wr * 64 + i * 16 + g * 4) = pk;
      }
    }
    __syncthreads();
    const int r0 = tid >> 4, ch = tid & 15;
#pragma unroll
    for (int p = 0; p < 8; ++p) {
      int nl = p * 16 + r0;
      int ng = n0 + nl, hh = ng >> 6, dd = ng & 63;
      *(u32x4*)(Vt + (size_t)((bb * H_ + hh) * D_ + dd) * S_ + s0 + ch * 8) =
          *(const u32x4*)(Ct + nl * 132 + ch * 8);
    }
  } else {
    const float scale = (z == 0) ? SCALE_ : 1.0f;
#pragma unroll
    for (int j = 0; j < 4; ++j) {
      int nl = wc * 64 + j * 16 + l15;
      float bvv = bias[n0 + nl];
#pragma unroll
      for (int i = 0; i < 4; ++i)
#pragma unroll
        for (int r = 0; r < 4; ++r)
          Ct[(wr * 64 + i * 16 + g * 4 + r) * 132 + nl] =
              f2bf((acc[i][j][r] + bvv) * scale);
    }
    __syncthreads();
    u16* outp = (z == 0) ? Qbf : Kbf;
    const int u0 = tid >> 3, ch = tid & 7;
#pragma unroll
    for (int p = 0; p < 8; ++p) {
      int u = p * 32 + u0;
      int ml = u >> 1, nh = u & 1;
      int hh = (n0 >> 6) + nh;
      *(u32x4*)(outp + (size_t)((bb * H_ + hh) * S_ + s0 + ml) * D_ + ch * 8) =
          *(const u32x4*)(Ct + ml * 132 + nh * 64 + ch * 8);
    }
  }
}

// ---------------------------------------------------------------------------
// Causal flash attention (round-15 version, verbatim): XCD-local K/V
// (b = bid&7 -> one batch per XCD, 3MB L2-resident) + balanced qb trio.
// ---------------------------------------------------------------------------
__launch_bounds__(256)
__global__ void attn_kernel(const u16* __restrict__ Qbf, const u16* __restrict__ Kbf,
                            const u16* __restrict__ Vt, u16* __restrict__ concat) {
  __shared__ __align__(16) u16 Ks[2][64 * 64];
  __shared__ __align__(16) u16 Vs[2][64 * 64];
  __shared__ __align__(16) u16 Ps[4][2][16 * 64];
  const int tid = threadIdx.x;
  const int lane = tid & 63;
  const int w = tid >> 6;
  const int l15 = lane & 15;
  const int g = lane >> 4;
  const int bid = blockIdx.x;
  const int b = bid & 7;                // batch == XCD
  const int r = bid >> 3;               // 0..95
  const int y = r & 7;                  // qb slot
  const int h = r >> 3;                 // 0..11 head within batch
  const int qb = (h < 4) ? y
               : (h < 8) ? ((y + 3) & 7)
               : (int)((0x13502467u >> (4 * y)) & 7u);
  const u16* Qb = Qbf + (b * H_ + h) * S_ * D_;
  const u16* Kb = Kbf + (b * H_ + h) * S_ * D_;
  const u16* Vb = Vt  + (b * H_ + h) * D_ * S_;
  const int q0 = qb * 128;
  const int qrow_base = q0 + w * 32;

  s16x8 qf[2][2];
#pragma unroll
  for (int qg = 0; qg < 2; ++qg)
#pragma unroll
    for (int kk = 0; kk < 2; ++kk)
      qf[qg][kk] = *(const s16x8*)(Qb + (qrow_base + qg * 16 + l15) * D_ + kk * 32 + g * 8);

  f32x4 o[2][4];
#pragma unroll
  for (int qg = 0; qg < 2; ++qg)
#pragma unroll
    for (int dc = 0; dc < 4; ++dc) o[qg][dc] = (f32x4){0.f, 0.f, 0.f, 0.f};
  float lsum[2] = {0.f, 0.f};

  const int nt = 2 * qb + 2;
  const int srow = lane >> 3;
  const int schunk = lane & 7;

#define STAGE(tt, bsel)                                                              \
  {                                                                                  \
    const int t0s = (tt) * 64;                                                       \
    _Pragma("unroll")                                                                \
    for (int j = 0; j < 2; ++j) {                                                    \
      int row = w * 16 + j * 8 + srow;                                               \
      GLOAD_LDS16(Kb + (t0s + row) * D_ + ((schunk ^ (row & 7)) << 3),               \
                  &Ks[bsel][(w * 16 + j * 8) * 64]);                                 \
      GLOAD_LDS16(Vb + row * S_ + t0s + ((schunk ^ (row & 7)) << 3),                 \
                  &Vs[bsel][(w * 16 + j * 8) * 64]);                                 \
    }                                                                                \
  }

  STAGE(0, 0);
  __syncthreads();
  int cur = 0;
  for (int t = 0; t < nt; ++t) {
    if (t + 1 < nt) STAGE(t + 1, cur ^ 1);
    const int t0 = t * 64;
    const u16* Kl = Ks[cur];
    const u16* Vl = Vs[cur];
    f32x4 st[2][4];
#pragma unroll
    for (int qg = 0; qg < 2; ++qg)
#pragma unroll
      for (int c = 0; c < 4; ++c) st[qg][c] = (f32x4){0.f, 0.f, 0.f, 0.f};
#pragma unroll
    for (int kk = 0; kk < 2; ++kk) {
      s16x8 kf[4];
#pragma unroll
      for (int c = 0; c < 4; ++c) {
        int row = 16 * c + l15;
        kf[c] = *(const s16x8*)(Kl + row * 64 + ((((kk << 2) + g) ^ (row & 7)) << 3));
      }
#pragma unroll
      for (int qg = 0; qg < 2; ++qg)
#pragma unroll
        for (int c = 0; c < 4; ++c) st[qg][c] = MFMA16(kf[c], qf[qg][kk], st[qg][c]);
    }
#pragma unroll
    for (int qg = 0; qg < 2; ++qg) {
      const int qmin = qrow_base + qg * 16;
      if (t0 > qmin + 15) continue;
      const bool needmask = (t0 + 63 > qmin);
      const int qv = qmin + l15;
      u16* Pq = Ps[w][qg];
      float lacc = 0.f;
#pragma unroll
      for (int c = 0; c < 4; ++c) {
        float p[4];
#pragma unroll
        for (int r2 = 0; r2 < 4; ++r2) {
          float s = st[qg][c][r2];
          if (needmask && (t0 + 16 * c + 4 * g + r2 > qv)) s = -1e30f;
          p[r2] = __expf(s);
          lacc += p[r2];
        }
        int chunk = (2 * c + (g >> 1)) ^ (l15 & 7);
        *(uint2*)(Pq + l15 * 64 + (chunk << 3) + ((g & 1) << 2)) =
            make_uint2(pack2(p[0], p[1]), pack2(p[2], p[3]));
      }
      lsum[qg] += lacc;
    }
    asm volatile("s_waitcnt lgkmcnt(0)" ::: "memory");
    __builtin_amdgcn_sched_barrier(0);
#pragma unroll
    for (int kk = 0; kk < 2; ++kk) {
      s16x8 vf[4];
#pragma unroll
      for (int dc = 0; dc < 4; ++dc) {
        int row = 16 * dc + l15;
        vf[dc] = *(const s16x8*)(Vl + row * 64 + ((((kk << 2) + g) ^ (row & 7)) << 3));
      }
#pragma unroll
      for (int qg = 0; qg < 2; ++qg) {
        if (t0 > qrow_base + qg * 16 + 15) continue;
        s16x8 pf = *(const s16x8*)(Ps[w][qg] + l15 * 64 +
                                   ((((kk << 2) + g) ^ (l15 & 7)) << 3));
#pragma unroll
        for (int dc = 0; dc < 4; ++dc) o[qg][dc] = MFMA16(vf[dc], pf, o[qg][dc]);
      }
    }
    __syncthreads();
    cur ^= 1;
  }
#pragma unroll
  for (int qg = 0; qg < 2; ++qg) {
    float l = lsum[qg];
    l += __shfl_xor(l, 16);
    l += __shfl_xor(l, 32);
    float linv = 1.0f / l;
    int q = qrow_base + qg * 16 + l15;
    u16* Cr = concat + (b * S_ + q) * HD_ + h * D_;
#pragma unroll
    for (int dc = 0; dc < 4; ++dc) {
      *(uint2*)(Cr + dc * 16 + g * 4) =
          make_uint2(pack2(o[qg][dc][0] * linv, o[qg][dc][1] * linv),
                     pack2(o[qg][dc][2] * linv, o[qg][dc][3] * linv));
    }
  }
#undef STAGE
}

// ---------------------------------------------------------------------------
// Output projection (round-12 version, verbatim): single-buffer, 32KB, 2D grid.
// ---------------------------------------------------------------------------
__launch_bounds__(256)
__global__ void out_gemm(const u16* __restrict__ concat, const u16* __restrict__ Wot,
                         const float* __restrict__ bo, float* __restrict__ out) {
  __shared__ __align__(16) u16 As[128 * 64];
  __shared__ __align__(16) u16 Bs[128 * 64];
  const int tid = threadIdx.x;
  const int lane = tid & 63;
  const int w = tid >> 6;
  const int wr = w >> 1, wc = w & 1;
  const int m0 = blockIdx.x * 128;
  const int n0 = blockIdx.y * 128;
  f32x4 acc[4][4];
#pragma unroll
  for (int i = 0; i < 4; ++i)
#pragma unroll
    for (int j = 0; j < 4; ++j) acc[i][j] = (f32x4){0.f, 0.f, 0.f, 0.f};
  const int g = lane >> 4;
  const int l15 = lane & 15;
  const int srow = lane >> 3;
  const int sch  = (lane & 7) ^ srow;

  for (int kt = 0; kt < HD_ / 64; ++kt) {
    __syncthreads();
#pragma unroll
    for (int i = 0; i < 4; ++i) {
      int row = i * 32 + w * 8 + srow;
      GLOAD_LDS16(concat + (m0 + row) * HD_ + kt * 64 + sch * 8, &As[(i * 32 + w * 8) * 64]);
      GLOAD_LDS16(Wot    + (n0 + row) * HD_ + kt * 64 + sch * 8, &Bs[(i * 32 + w * 8) * 64]);
    }
    __syncthreads();
#pragma unroll
    for (int kk = 0; kk < 2; ++kk) {
      const int kc = kk * 4 + g;
      s16x8 af[4], bfr[4];
#pragma unroll
      for (int i = 0; i < 4; ++i) {
        int row = wr * 64 + i * 16 + l15;
        af[i] = *(const s16x8*)(As + row * 64 + ((kc ^ (row & 7)) << 3));
      }
#pragma unroll
      for (int j = 0; j < 4; ++j) {
        int row = wc * 64 + j * 16 + l15;
        bfr[j] = *(const s16x8*)(Bs + row * 64 + ((kc ^ (row & 7)) << 3));
      }
#pragma unroll
      for (int i = 0; i < 4; ++i)
#pragma unroll
        for (int j = 0; j < 4; ++j) acc[i][j] = MFMA16(af[i], bfr[j], acc[i][j]);
    }
  }
#pragma unroll
  for (int j = 0; j < 4; ++j) {
    int ng = n0 + wc * 64 + j * 16 + l15;
    float bvv = bo[ng];
#pragma unroll
    for (int i = 0; i < 4; ++i) {
      int mrow = m0 + wr * 64 + i * 16 + g * 4;
#pragma unroll
      for (int r = 0; r < 4; ++r) out[(mrow + r) * E_ + ng] = acc[i][j][r] + bvv;
    }
  }
}

extern "C" void kernel_launch(void* const* d_in, const int* in_sizes, int n_in,
                              void* d_out, int out_size, void* d_ws, size_t ws_size,
                              hipStream_t stream) {
  const float* queries = (const float*)d_in[0];
  const float* keys    = (const float*)d_in[1];
  const float* values  = (const float*)d_in[2];
  // d_in[3] = attn_mask (causal tril; handled analytically)
  const float* Wq = (const float*)d_in[4];
  const float* bq = (const float*)d_in[5];
  const float* Wk = (const float*)d_in[6];
  const float* bk = (const float*)d_in[7];
  const float* Wv = (const float*)d_in[8];
  const float* bv = (const float*)d_in[9];
  const float* Wo = (const float*)d_in[10];
  const float* bo = (const float*)d_in[11];
  float* out = (float*)d_out;

  u16* Wt_qkv = (u16*)d_ws;                   // 3*768*768
  u16* Wot    = Wt_qkv + 3 * HD_ * E_;        // 768*768
  u16* Qbf    = Wot + E_ * HD_;               // B*H*S*D
  u16* Kbf    = Qbf + B_ * H_ * S_ * D_;
  u16* Vt     = Kbf + B_ * H_ * S_ * D_;
  u16* concat = Vt  + B_ * H_ * S_ * D_;      // B*S*HD

  prep_weights<<<dim3(576), dim3(256), 0, stream>>>(Wq, Wk, Wv, Wo, Wt_qkv, Wot);
  qkv_gemm<<<dim3(6, 64, 3), dim3(256), 0, stream>>>(
      queries, keys, values, Wt_qkv, bq, bk, bv, Qbf, Kbf, Vt);
  attn_kernel<<<dim3(768), dim3(256), 0, stream>>>(Qbf, Kbf, Vt, concat);
  out_gemm<<<dim3(64, 6), dim3(256), 0, stream>>>(concat, Wot, bo, out);
}

// Round 17
// 124.798 us; speedup vs baseline: 1.1885x; 1.1885x over previous
//
#include <hip/hip_runtime.h>

#define B_ 8
#define S_ 1024
#define E_ 768
#define H_ 12
#define D_ 64
#define HD_ 768
#define SCALE_ 0.125f

typedef short s16x8 __attribute__((ext_vector_type(8)));
typedef float f32x4 __attribute__((ext_vector_type(4)));
typedef unsigned int u32x4 __attribute__((ext_vector_type(4)));
typedef unsigned short u16;
typedef unsigned int u32;

#define MFMA16(a,b,c) __builtin_amdgcn_mfma_f32_16x16x32_bf16((a),(b),(c),0,0,0)

__device__ __forceinline__ u16 f2bf(float x){
  unsigned u = __float_as_uint(x);
  u += 0x7fffu + ((u >> 16) & 1u);
  return (u16)(u >> 16);
}

__device__ __forceinline__ u32 pack2(float a, float b){
  return (u32)f2bf(a) | ((u32)f2bf(b) << 16);
}

// HW packed f32->bf16 (RNE). No builtin on gfx950 (m240) -> inline asm.
__device__ __forceinline__ u32 cvtpk(float a, float b){
  u32 r;
  asm("v_cvt_pk_bf16_f32 %0, %1, %2" : "=v"(r) : "v"(a), "v"(b));
  return r;
}

#define GLOAD_LDS16(srcp, dstp)                                                        \
  __builtin_amdgcn_global_load_lds(                                                    \
      (const __attribute__((address_space(1))) u32*)(srcp),                            \
      (__attribute__((address_space(3))) u32*)(dstp), 16, 0, 0)

// ---------------------------------------------------------------------------
// Weight prep (coalesced, LDS 64x65 transpose tiles):
//   blocks 0..431 : Wq/Wk/Wv [H,E,D] -> Wt_qkv[z][n=h*64+d][e]
//   blocks 432..575: Wo [HD,E] -> Wot[n][k]
// ---------------------------------------------------------------------------
__global__ void prep_weights(const float* __restrict__ Wq, const float* __restrict__ Wk,
                             const float* __restrict__ Wv, const float* __restrict__ Wo,
                             u16* __restrict__ Wt_qkv, u16* __restrict__ Wot) {
  __shared__ float t[64][65];
  const int bid = blockIdx.x;
  const int tid = threadIdx.x;
  const int c = tid & 63;
  const int rg = tid >> 6;
  if (bid < 432) {
    int z = bid / 144, r = bid % 144, h = r / 12, et = r % 12;
    const float* W = (z == 0) ? Wq : ((z == 1) ? Wk : Wv);
    const float* src = W + (size_t)(h * E_ + et * 64) * D_;
#pragma unroll
    for (int p = 0; p < 16; ++p)
      t[rg + 4 * p][c] = src[(rg + 4 * p) * D_ + c];
    __syncthreads();
    u16* dst = Wt_qkv + (size_t)z * HD_ * E_ + (h * 64) * E_ + et * 64;
#pragma unroll
    for (int p = 0; p < 16; ++p) {
      int d = rg + 4 * p;
      dst[d * E_ + c] = f2bf(t[c][d]);
    }
  } else {
    int r = bid - 432; int kt = r / 12, nt = r % 12;
    const float* src = Wo + (size_t)(kt * 64) * E_ + nt * 64;
#pragma unroll
    for (int p = 0; p < 16; ++p)
      t[rg + 4 * p][c] = src[(rg + 4 * p) * E_ + c];
    __syncthreads();
    u16* dst = Wot + (size_t)(nt * 64) * HD_ + kt * 64;
#pragma unroll
    for (int p = 0; p < 16; ++p) {
      int nl = rg + 4 * p;
      dst[nl * HD_ + c] = f2bf(t[c][nl]);
    }
  }
}

// ---------------------------------------------------------------------------
// QKV projection GEMM (round-12 winner, verbatim): fused fp32-A body with
// LDS-bounce epilogue (coalesced 128/256B row stores). 49KB -> 3 blocks/CU.
// Grid (64,6,3): m fastest -> A re-reads are temporally separated (one full
// m-pass apart) so L3 absorbs them; adjacency-sharing across XCDs was a 3x
// FETCH regression (r16 lesson).
// z==0 -> Qbf [B,H,S,D] (pre-scaled); z==1 -> Kbf; z==2 -> Vt [B,H,D,S].
// ---------------------------------------------------------------------------
__launch_bounds__(256)
__global__ void qkv_gemm(const float* __restrict__ qin, const float* __restrict__ kin,
                         const float* __restrict__ vin, const u16* __restrict__ Wt_qkv,
                         const float* __restrict__ bq, const float* __restrict__ bk,
                         const float* __restrict__ bv, u16* __restrict__ Qbf,
                         u16* __restrict__ Kbf, u16* __restrict__ Vt) {
  __shared__ __align__(16) u16 SMEM[128 * 132];   // 33 KB: fp32 A tile / C bounce
  __shared__ __align__(16) u16 Bs[128 * 64];      // 16 KB bf16 B tile
  float* Asf = (float*)SMEM;                      // first 32 KB during K-loop
  const int tid = threadIdx.x;
  const int lane = tid & 63;
  const int w = tid >> 6;
  const int wr = w >> 1, wc = w & 1;
  const int m0 = blockIdx.x * 128;
  const int n0 = blockIdx.y * 128;
  const int z  = blockIdx.z;
  const float* in = (z == 0) ? qin : ((z == 1) ? kin : vin);
  const u16* Wt = Wt_qkv + z * (HD_ * E_);
  const float* bias = (z == 0) ? bq : ((z == 1) ? bk : bv);

  f32x4 acc[4][4];
#pragma unroll
  for (int i = 0; i < 4; ++i)
#pragma unroll
    for (int j = 0; j < 4; ++j) acc[i][j] = (f32x4){0.f, 0.f, 0.f, 0.f};

  const int g = lane >> 4;
  const int l15 = lane & 15;
  const int arow = lane >> 4;          // 0..3 within 4-row slab
  const int ach  = lane & 15;          // 16B chunk within 256B row
  const int brow = lane >> 3;          // 0..7
  const int bch  = lane & 7;

  for (int kt = 0; kt < E_ / 64; ++kt) {
    __syncthreads();
#pragma unroll
    for (int i = 0; i < 8; ++i) {       // A: 128 rows, 4 per wave-pass
      int row = i * 16 + w * 4 + arow;
      GLOAD_LDS16(in + (size_t)(m0 + row) * E_ + kt * 64 + ((ach ^ (row & 15)) << 2),
                  &Asf[(i * 16 + w * 4) * 64]);
    }
#pragma unroll
    for (int j = 0; j < 4; ++j) {       // B: 128 rows, 8 per wave-pass
      int row = j * 32 + w * 8 + brow;
      GLOAD_LDS16(Wt + (n0 + row) * E_ + kt * 64 + ((bch ^ (row & 7)) << 3),
                  &Bs[(j * 32 + w * 8) * 64]);
    }
    __syncthreads();
#pragma unroll
    for (int kk = 0; kk < 2; ++kk) {
      const int kc = kk * 4 + g;
      s16x8 af[4], bfr[4];
#pragma unroll
      for (int i = 0; i < 4; ++i) {
        int row = wr * 64 + i * 16 + l15;
        const float* rp = Asf + row * 64;
        f32x4 lo = *(const f32x4*)(rp + (((2 * kc)     ^ (row & 15)) << 2));
        f32x4 hi = *(const f32x4*)(rp + (((2 * kc + 1) ^ (row & 15)) << 2));
        u32x4 q;
        q[0] = cvtpk(lo[0], lo[1]);
        q[1] = cvtpk(lo[2], lo[3]);
        q[2] = cvtpk(hi[0], hi[1]);
        q[3] = cvtpk(hi[2], hi[3]);
        af[i] = __builtin_bit_cast(s16x8, q);
      }
#pragma unroll
      for (int j = 0; j < 4; ++j) {
        int row = wc * 64 + j * 16 + l15;
        bfr[j] = *(const s16x8*)(Bs + row * 64 + ((kc ^ (row & 7)) << 3));
      }
#pragma unroll
      for (int i = 0; i < 4; ++i)
#pragma unroll
        for (int j = 0; j < 4; ++j) acc[i][j] = MFMA16(af[i], bfr[j], acc[i][j]);
    }
  }
  // ---- epilogue: LDS bounce -> coalesced row stores.
  __syncthreads();                       // close all K-loop LDS reads
  const int bb = m0 >> 10;
  const int s0 = m0 & 1023;
  u16* Ct = SMEM;                        // [row][132] padded bounce tile
  if (z == 2) {
#pragma unroll
    for (int j = 0; j < 4; ++j) {
      int nl = wc * 64 + j * 16 + l15;
      float bvv = bias[n0 + nl];
#pragma unroll
      for (int i = 0; i < 4; ++i) {
        uint2 pk = make_uint2(pack2(acc[i][j][0] + bvv, acc[i][j][1] + bvv),
                              pack2(acc[i][j][2] + bvv, acc[i][j][3] + bvv));
        *(uint2*)(Ct + nl * 132 + wr * 64 + i * 16 + g * 4) = pk;
      }
    }
    __syncthreads();
    const int r0 = tid >> 4, ch = tid & 15;
#pragma unroll
    for (int p = 0; p < 8; ++p) {
      int nl = p * 16 + r0;
      int ng = n0 + nl, hh = ng >> 6, dd = ng & 63;
      *(u32x4*)(Vt + (size_t)((bb * H_ + hh) * D_ + dd) * S_ + s0 + ch * 8) =
          *(const u32x4*)(Ct + nl * 132 + ch * 8);
    }
  } else {
    const float scale = (z == 0) ? SCALE_ : 1.0f;
#pragma unroll
    for (int j = 0; j < 4; ++j) {
      int nl = wc * 64 + j * 16 + l15;
      float bvv = bias[n0 + nl];
#pragma unroll
      for (int i = 0; i < 4; ++i)
#pragma unroll
        for (int r = 0; r < 4; ++r)
          Ct[(wr * 64 + i * 16 + g * 4 + r) * 132 + nl] =
              f2bf((acc[i][j][r] + bvv) * scale);
    }
    __syncthreads();
    u16* outp = (z == 0) ? Qbf : Kbf;
    const int u0 = tid >> 3, ch = tid & 7;
#pragma unroll
    for (int p = 0; p < 8; ++p) {
      int u = p * 32 + u0;
      int ml = u >> 1, nh = u & 1;
      int hh = (n0 >> 6) + nh;
      *(u32x4*)(outp + (size_t)((bb * H_ + hh) * S_ + s0 + ml) * D_ + ch * 8) =
          *(const u32x4*)(Ct + ml * 132 + nh * 64 + ch * 8);
    }
  }
}

// ---------------------------------------------------------------------------
// Causal flash attention (round-15 version, verbatim): XCD-local K/V
// (b = bid&7 -> one batch per XCD, 3MB L2-resident) + balanced qb trio.
// ---------------------------------------------------------------------------
__launch_bounds__(256)
__global__ void attn_kernel(const u16* __restrict__ Qbf, const u16* __restrict__ Kbf,
                            const u16* __restrict__ Vt, u16* __restrict__ concat) {
  __shared__ __align__(16) u16 Ks[2][64 * 64];
  __shared__ __align__(16) u16 Vs[2][64 * 64];
  __shared__ __align__(16) u16 Ps[4][2][16 * 64];
  const int tid = threadIdx.x;
  const int lane = tid & 63;
  const int w = tid >> 6;
  const int l15 = lane & 15;
  const int g = lane >> 4;
  const int bid = blockIdx.x;
  const int b = bid & 7;                // batch == XCD
  const int r = bid >> 3;               // 0..95
  const int y = r & 7;                  // qb slot
  const int h = r >> 3;                 // 0..11 head within batch
  const int qb = (h < 4) ? y
               : (h < 8) ? ((y + 3) & 7)
               : (int)((0x13502467u >> (4 * y)) & 7u);
  const u16* Qb = Qbf + (b * H_ + h) * S_ * D_;
  const u16* Kb = Kbf + (b * H_ + h) * S_ * D_;
  const u16* Vb = Vt  + (b * H_ + h) * D_ * S_;
  const int q0 = qb * 128;
  const int qrow_base = q0 + w * 32;

  s16x8 qf[2][2];
#pragma unroll
  for (int qg = 0; qg < 2; ++qg)
#pragma unroll
    for (int kk = 0; kk < 2; ++kk)
      qf[qg][kk] = *(const s16x8*)(Qb + (qrow_base + qg * 16 + l15) * D_ + kk * 32 + g * 8);

  f32x4 o[2][4];
#pragma unroll
  for (int qg = 0; qg < 2; ++qg)
#pragma unroll
    for (int dc = 0; dc < 4; ++dc) o[qg][dc] = (f32x4){0.f, 0.f, 0.f, 0.f};
  float lsum[2] = {0.f, 0.f};

  const int nt = 2 * qb + 2;
  const int srow = lane >> 3;
  const int schunk = lane & 7;

#define STAGE(tt, bsel)                                                              \
  {                                                                                  \
    const int t0s = (tt) * 64;                                                       \
    _Pragma("unroll")                                                                \
    for (int j = 0; j < 2; ++j) {                                                    \
      int row = w * 16 + j * 8 + srow;                                               \
      GLOAD_LDS16(Kb + (t0s + row) * D_ + ((schunk ^ (row & 7)) << 3),               \
                  &Ks[bsel][(w * 16 + j * 8) * 64]);                                 \
      GLOAD_LDS16(Vb + row * S_ + t0s + ((schunk ^ (row & 7)) << 3),                 \
                  &Vs[bsel][(w * 16 + j * 8) * 64]);                                 \
    }                                                                                \
  }

  STAGE(0, 0);
  __syncthreads();
  int cur = 0;
  for (int t = 0; t < nt; ++t) {
    if (t + 1 < nt) STAGE(t + 1, cur ^ 1);
    const int t0 = t * 64;
    const u16* Kl = Ks[cur];
    const u16* Vl = Vs[cur];
    f32x4 st[2][4];
#pragma unroll
    for (int qg = 0; qg < 2; ++qg)
#pragma unroll
      for (int c = 0; c < 4; ++c) st[qg][c] = (f32x4){0.f, 0.f, 0.f, 0.f};
#pragma unroll
    for (int kk = 0; kk < 2; ++kk) {
      s16x8 kf[4];
#pragma unroll
      for (int c = 0; c < 4; ++c) {
        int row = 16 * c + l15;
        kf[c] = *(const s16x8*)(Kl + row * 64 + ((((kk << 2) + g) ^ (row & 7)) << 3));
      }
#pragma unroll
      for (int qg = 0; qg < 2; ++qg)
#pragma unroll
        for (int c = 0; c < 4; ++c) st[qg][c] = MFMA16(kf[c], qf[qg][kk], st[qg][c]);
    }
#pragma unroll
    for (int qg = 0; qg < 2; ++qg) {
      const int qmin = qrow_base + qg * 16;
      if (t0 > qmin + 15) continue;
      const bool needmask = (t0 + 63 > qmin);
      const int qv = qmin + l15;
      u16* Pq = Ps[w][qg];
      float lacc = 0.f;
#pragma unroll
      for (int c = 0; c < 4; ++c) {
        float p[4];
#pragma unroll
        for (int r2 = 0; r2 < 4; ++r2) {
          float s = st[qg][c][r2];
          if (needmask && (t0 + 16 * c + 4 * g + r2 > qv)) s = -1e30f;
          p[r2] = __expf(s);
          lacc += p[r2];
        }
        int chunk = (2 * c + (g >> 1)) ^ (l15 & 7);
        *(uint2*)(Pq + l15 * 64 + (chunk << 3) + ((g & 1) << 2)) =
            make_uint2(pack2(p[0], p[1]), pack2(p[2], p[3]));
      }
      lsum[qg] += lacc;
    }
    asm volatile("s_waitcnt lgkmcnt(0)" ::: "memory");
    __builtin_amdgcn_sched_barrier(0);
#pragma unroll
    for (int kk = 0; kk < 2; ++kk) {
      s16x8 vf[4];
#pragma unroll
      for (int dc = 0; dc < 4; ++dc) {
        int row = 16 * dc + l15;
        vf[dc] = *(const s16x8*)(Vl + row * 64 + ((((kk << 2) + g) ^ (row & 7)) << 3));
      }
#pragma unroll
      for (int qg = 0; qg < 2; ++qg) {
        if (t0 > qrow_base + qg * 16 + 15) continue;
        s16x8 pf = *(const s16x8*)(Ps[w][qg] + l15 * 64 +
                                   ((((kk << 2) + g) ^ (l15 & 7)) << 3));
#pragma unroll
        for (int dc = 0; dc < 4; ++dc) o[qg][dc] = MFMA16(vf[dc], pf, o[qg][dc]);
      }
    }
    __syncthreads();
    cur ^= 1;
  }
#pragma unroll
  for (int qg = 0; qg < 2; ++qg) {
    float l = lsum[qg];
    l += __shfl_xor(l, 16);
    l += __shfl_xor(l, 32);
    float linv = 1.0f / l;
    int q = qrow_base + qg * 16 + l15;
    u16* Cr = concat + (b * S_ + q) * HD_ + h * D_;
#pragma unroll
    for (int dc = 0; dc < 4; ++dc) {
      *(uint2*)(Cr + dc * 16 + g * 4) =
          make_uint2(pack2(o[qg][dc][0] * linv, o[qg][dc][1] * linv),
                     pack2(o[qg][dc][2] * linv, o[qg][dc][3] * linv));
    }
  }
#undef STAGE
}

// ---------------------------------------------------------------------------
// Output projection (round-12 version, verbatim): single-buffer, 32KB, 2D grid.
// ---------------------------------------------------------------------------
__launch_bounds__(256)
__global__ void out_gemm(const u16* __restrict__ concat, const u16* __restrict__ Wot,
                         const float* __restrict__ bo, float* __restrict__ out) {
  __shared__ __align__(16) u16 As[128 * 64];
  __shared__ __align__(16) u16 Bs[128 * 64];
  const int tid = threadIdx.x;
  const int lane = tid & 63;
  const int w = tid >> 6;
  const int wr = w >> 1, wc = w & 1;
  const int m0 = blockIdx.x * 128;
  const int n0 = blockIdx.y * 128;
  f32x4 acc[4][4];
#pragma unroll
  for (int i = 0; i < 4; ++i)
#pragma unroll
    for (int j = 0; j < 4; ++j) acc[i][j] = (f32x4){0.f, 0.f, 0.f, 0.f};
  const int g = lane >> 4;
  const int l15 = lane & 15;
  const int srow = lane >> 3;
  const int sch  = (lane & 7) ^ srow;

  for (int kt = 0; kt < HD_ / 64; ++kt) {
    __syncthreads();
#pragma unroll
    for (int i = 0; i < 4; ++i) {
      int row = i * 32 + w * 8 + srow;
      GLOAD_LDS16(concat + (m0 + row) * HD_ + kt * 64 + sch * 8, &As[(i * 32 + w * 8) * 64]);
      GLOAD_LDS16(Wot    + (n0 + row) * HD_ + kt * 64 + sch * 8, &Bs[(i * 32 + w * 8) * 64]);
    }
    __syncthreads();
#pragma unroll
    for (int kk = 0; kk < 2; ++kk) {
      const int kc = kk * 4 + g;
      s16x8 af[4], bfr[4];
#pragma unroll
      for (int i = 0; i < 4; ++i) {
        int row = wr * 64 + i * 16 + l15;
        af[i] = *(const s16x8*)(As + row * 64 + ((kc ^ (row & 7)) << 3));
      }
#pragma unroll
      for (int j = 0; j < 4; ++j) {
        int row = wc * 64 + j * 16 + l15;
        bfr[j] = *(const s16x8*)(Bs + row * 64 + ((kc ^ (row & 7)) << 3));
      }
#pragma unroll
      for (int i = 0; i < 4; ++i)
#pragma unroll
        for (int j = 0; j < 4; ++j) acc[i][j] = MFMA16(af[i], bfr[j], acc[i][j]);
    }
  }
#pragma unroll
  for (int j = 0; j < 4; ++j) {
    int ng = n0 + wc * 64 + j * 16 + l15;
    float bvv = bo[ng];
#pragma unroll
    for (int i = 0; i < 4; ++i) {
      int mrow = m0 + wr * 64 + i * 16 + g * 4;
#pragma unroll
      for (int r = 0; r < 4; ++r) out[(mrow + r) * E_ + ng] = acc[i][j][r] + bvv;
    }
  }
}

extern "C" void kernel_launch(void* const* d_in, const int* in_sizes, int n_in,
                              void* d_out, int out_size, void* d_ws, size_t ws_size,
                              hipStream_t stream) {
  const float* queries = (const float*)d_in[0];
  const float* keys    = (const float*)d_in[1];
  const float* values  = (const float*)d_in[2];
  // d_in[3] = attn_mask (causal tril; handled analytically)
  const float* Wq = (const float*)d_in[4];
  const float* bq = (const float*)d_in[5];
  const float* Wk = (const float*)d_in[6];
  const float* bk = (const float*)d_in[7];
  const float* Wv = (const float*)d_in[8];
  const float* bv = (const float*)d_in[9];
  const float* Wo = (const float*)d_in[10];
  const float* bo = (const float*)d_in[11];
  float* out = (float*)d_out;

  u16* Wt_qkv = (u16*)d_ws;                   // 3*768*768
  u16* Wot    = Wt_qkv + 3 * HD_ * E_;        // 768*768
  u16* Qbf    = Wot + E_ * HD_;               // B*H*S*D
  u16* Kbf    = Qbf + B_ * H_ * S_ * D_;
  u16* Vt     = Kbf + B_ * H_ * S_ * D_;
  u16* concat = Vt  + B_ * H_ * S_ * D_;      // B*S*HD

  prep_weights<<<dim3(576), dim3(256), 0, stream>>>(Wq, Wk, Wv, Wo, Wt_qkv, Wot);
  qkv_gemm<<<dim3(64, 6, 3), dim3(256), 0, stream>>>(
      queries, keys, values, Wt_qkv, bq, bk, bv, Qbf, Kbf, Vt);
  attn_kernel<<<dim3(768), dim3(256), 0, stream>>>(Qbf, Kbf, Vt, concat);
  out_gemm<<<dim3(64, 6), dim3(256), 0, stream>>>(concat, Wot, bo, out);
}